// Round 1
// baseline (72.397 us; speedup 1.0000x reference)
//
#include <hip/hip_runtime.h>

// Problem constants (fixed by setup_inputs): B=1, C=128, D*H*W = N = 16384, AGE=64.
// Algebraic identity: K and V rows are identical across pixels (age is broadcast),
// so softmax weights are exactly uniform (1/N) and attended == v_vec.
// out[n][c] = pixel[c][n] + (Wv @ age + bv)[c]   -- a transpose + broadcast add.
#define CC     128
#define NN     16384
#define AGEDIM 64
#define TC     32     // c-extent of a tile
#define TN     128    // n-extent of a tile

__global__ __launch_bounds__(256) void CrossAttention_19387482374277_kernel(
    const float* __restrict__ px,   // [C][N] = pixel_features flattened
    const float* __restrict__ age,  // [AGE]
    const float* __restrict__ Wv,   // [C][AGE]
    const float* __restrict__ bv,   // [C]
    float* __restrict__ out)        // [N][C]
{
    __shared__ float tile[TC][TN + 1];  // +1 pad: read-along-c becomes 2-way (free)
    __shared__ float vvec[TC];

    const int t = threadIdx.x;
    const int nTilesN = NN / TN;              // 128
    const int cTile = blockIdx.x / nTilesN;   // 0..3
    const int nTile = blockIdx.x % nTilesN;   // 0..127
    const int c0 = cTile * TC;
    const int n0 = nTile * TN;

    // ---- Load 32x128 tile, coalesced along n (float4 = 16B/lane) ----
    const int n4 = (t & 31) * 4;   // n offset within tile
    const int cr = (t >> 5);       // 0..7
    #pragma unroll
    for (int i = 0; i < 4; ++i) {
        const int c = cr + i * 8;
        const float4 val = *reinterpret_cast<const float4*>(
            px + (size_t)(c0 + c) * NN + n0 + n4);
        tile[c][n4 + 0] = val.x;
        tile[c][n4 + 1] = val.y;
        tile[c][n4 + 2] = val.z;
        tile[c][n4 + 3] = val.w;
    }

    // ---- v_vec slice for this block's 32 channels (overlaps load latency) ----
    if (t < TC) {
        const int c = c0 + t;
        float acc = bv[c];
        #pragma unroll
        for (int a = 0; a < AGEDIM; ++a) acc += age[a] * Wv[c * AGEDIM + a];
        vvec[t] = acc;
    }

    __syncthreads();

    // ---- Store transposed + v_vec, coalesced along c (float4 = 16B/lane) ----
    const int c4 = (t & 7) * 4;    // c offset within tile
    const int nr = (t >> 3);       // 0..31
    #pragma unroll
    for (int i = 0; i < 4; ++i) {
        const int n = nr + i * 32;
        float4 o;
        o.x = tile[c4 + 0][n] + vvec[c4 + 0];
        o.y = tile[c4 + 1][n] + vvec[c4 + 1];
        o.z = tile[c4 + 2][n] + vvec[c4 + 2];
        o.w = tile[c4 + 3][n] + vvec[c4 + 3];
        *reinterpret_cast<float4*>(out + (size_t)(n0 + n) * CC + c0 + c4) = o;
    }
}

extern "C" void kernel_launch(void* const* d_in, const int* in_sizes, int n_in,
                              void* d_out, int out_size, void* d_ws, size_t ws_size,
                              hipStream_t stream) {
    // setup_inputs order: 0=pixel_features, 1=age_features, 2=Wq, 3=bq,
    //                     4=Wk, 5=bk, 6=Wv, 7=bv
    const float* px  = (const float*)d_in[0];
    const float* age = (const float*)d_in[1];
    const float* Wv  = (const float*)d_in[6];
    const float* bv  = (const float*)d_in[7];
    float* out = (float*)d_out;

    const dim3 grid((CC / TC) * (NN / TN));   // 4 * 128 = 512 blocks
    CrossAttention_19387482374277_kernel<<<grid, 256, 0, stream>>>(px, age, Wv, bv, out);
}